// Round 1
// baseline (1328.383 us; speedup 1.0000x reference)
//
#include <hip/hip_runtime.h>

typedef unsigned short UST;
typedef __attribute__((ext_vector_type(8))) __bf16 bf16x8;
typedef __attribute__((ext_vector_type(4))) float f32x4;

__device__ __forceinline__ float bf2f(UST u) {
    union { unsigned int i; float f; } v; v.i = ((unsigned int)u) << 16; return v.f;
}
__device__ __forceinline__ UST f2bf(float f) {
    union { float f; unsigned int i; } v; v.f = f;
    return (UST)((v.i + 0x7fffu + ((v.i >> 16) & 1u)) >> 16);
}

__device__ __forceinline__ void gl2lds16(const UST* g, UST* l) {
    __builtin_amdgcn_global_load_lds(
        (const __attribute__((address_space(1))) unsigned int*)g,
        (__attribute__((address_space(3))) unsigned int*)l, 16, 0, 0);
}

// ---------------------------------------------------------------------------
// Weight prep: W'[o,i] = (qw/15*2-1)*scale + sum_r lb[o,r]*la[r,i], cast bf16.
// Grid: (18 layers, 8 o-tiles, 8 i-tiles), 256 threads. Each thread: 8x8.
// ---------------------------------------------------------------------------
__global__ __launch_bounds__(256) void prep_w(
    const int* __restrict__ qw, const float* __restrict__ scale,
    const float* __restrict__ la, const float* __restrict__ lb,
    UST* __restrict__ wp)
{
    int l = blockIdx.x, ot = blockIdx.y, it = blockIdx.z;
    __shared__ float la_s[32 * 128];   // [r][i]
    __shared__ float lb_s[128 * 32];   // [o][r]
    const float* laL = la + (size_t)l * 32 * 1024;
    const float* lbL = lb + (size_t)l * 1024 * 32;
    int t = threadIdx.x;
    for (int e = t; e < 32 * 128; e += 256) {
        int r = e >> 7, i = e & 127;
        la_s[e] = laL[r * 1024 + it * 128 + i];
    }
    for (int e = t; e < 128 * 32; e += 256)
        lb_s[e] = lbL[(size_t)ot * 128 * 32 + e];
    __syncthreads();

    int o0 = (t >> 4) * 8;   // 0..120
    int i0 = (t & 15) * 8;   // 0..120
    float acc[8][8];
    #pragma unroll
    for (int a = 0; a < 8; a++)
        #pragma unroll
        for (int c = 0; c < 8; c++) acc[a][c] = 0.f;
    for (int r = 0; r < 32; ++r) {
        float bv[8], av[8];
        #pragma unroll
        for (int j = 0; j < 8; j++) bv[j] = lb_s[(o0 + j) * 32 + r];
        #pragma unroll
        for (int j = 0; j < 8; j++) av[j] = la_s[r * 128 + i0 + j];
        #pragma unroll
        for (int a = 0; a < 8; a++)
            #pragma unroll
            for (int c = 0; c < 8; c++) acc[a][c] += bv[a] * av[c];
    }

    const int* qL = qw + (size_t)l * 1024 * 1024;
    const float* sL = scale + (size_t)l * 1024 * 64;
    UST* wL = wp + (size_t)l * 1024 * 1024;
    #pragma unroll
    for (int a = 0; a < 8; a++) {
        int go = ot * 128 + o0 + a;
        int gi = it * 128 + i0;                 // 8 cols, all in one group of 16
        float s = sL[go * 64 + (gi >> 4)];
        UST o8[8];
        #pragma unroll
        for (int c = 0; c < 8; c++) {
            int q = qL[(size_t)go * 1024 + gi + c];
            float w = ((float)q * (2.0f / 15.0f) - 1.0f) * s + acc[a][c];
            o8[c] = f2bf(w);
        }
        *(ushort4*)(wL + (size_t)go * 1024 + gi) = make_ushort4(o8[0], o8[1], o8[2], o8[3]);
        *(ushort4*)(wL + (size_t)go * 1024 + gi + 4) = make_ushort4(o8[4], o8[5], o8[6], o8[7]);
    }
}

// ---------------------------------------------------------------------------
// x fp32 -> bf16
// ---------------------------------------------------------------------------
__global__ __launch_bounds__(256) void f32_to_bf16(const float* __restrict__ x,
                                                   UST* __restrict__ o)
{
    size_t i = ((size_t)blockIdx.x * 256 + threadIdx.x) * 4;
    float4 v = *(const float4*)(x + i);
    *(ushort4*)(o + i) = make_ushort4(f2bf(v.x), f2bf(v.y), f2bf(v.z), f2bf(v.w));
}

// ---------------------------------------------------------------------------
// GEMM: C[M,1024] = X[M,1024] @ W[1024,1024]^T (+bias, epilogue by mode)
//   mode 0: relu, bf16 out     mode 1: bf16 out     mode 2: +resid, fp32 out
// 128x128 tile, BK=32, 4 waves 2x2, mfma 16x16x32 bf16 4x4/wave.
// ---------------------------------------------------------------------------
#define BM 128
#define BN 128
#define BK 32

__global__ __launch_bounds__(256) void gemm_ep(
    const UST* __restrict__ X, const UST* __restrict__ W,
    const float* __restrict__ bias,
    UST* __restrict__ outb, const UST* __restrict__ resid,
    float* __restrict__ outf, int mode)
{
    const int K = 1024;
    __shared__ UST sA[BM * BK];
    __shared__ UST sB[BN * BK];
    int tid = threadIdx.x;
    int wave = tid >> 6, lane = tid & 63;
    int wm = wave >> 1, wn = wave & 1;
    int bm = blockIdx.x, bn = blockIdx.y;
    int la15 = lane & 15, qa = lane >> 4;

    int c0 = tid, c1 = tid + 256;             // 16B-chunk ids (512 per tile)
    int rowA0 = c0 >> 2, kc0 = (c0 & 3) * 8;  // 4 chunks per 32-elem row
    int rowA1 = c1 >> 2, kc1 = (c1 & 3) * 8;
    const UST* gA0 = X + (size_t)(bm * BM + rowA0) * K + kc0;
    const UST* gA1 = X + (size_t)(bm * BM + rowA1) * K + kc1;
    const UST* gB0 = W + (size_t)(bn * BN + rowA0) * K + kc0;
    const UST* gB1 = W + (size_t)(bn * BN + rowA1) * K + kc1;

    f32x4 acc[4][4];
    #pragma unroll
    for (int i = 0; i < 4; i++)
        #pragma unroll
        for (int j = 0; j < 4; j++) acc[i][j] = (f32x4){0.f, 0.f, 0.f, 0.f};

    for (int k0 = 0; k0 < K; k0 += BK) {
        gl2lds16(gA0 + k0, &sA[c0 * 8]);
        gl2lds16(gA1 + k0, &sA[c1 * 8]);
        gl2lds16(gB0 + k0, &sB[c0 * 8]);
        gl2lds16(gB1 + k0, &sB[c1 * 8]);
        asm volatile("s_waitcnt vmcnt(0)" ::: "memory");
        __syncthreads();

        bf16x8 af[4], bf[4];
        #pragma unroll
        for (int mi = 0; mi < 4; mi++)
            af[mi] = *(const bf16x8*)&sA[(wm * 64 + mi * 16 + la15) * BK + qa * 8];
        #pragma unroll
        for (int ni = 0; ni < 4; ni++)
            bf[ni] = *(const bf16x8*)&sB[(wn * 64 + ni * 16 + la15) * BK + qa * 8];
        #pragma unroll
        for (int mi = 0; mi < 4; mi++)
            #pragma unroll
            for (int ni = 0; ni < 4; ni++)
                acc[mi][ni] = __builtin_amdgcn_mfma_f32_16x16x32_bf16(
                    af[mi], bf[ni], acc[mi][ni], 0, 0, 0);
        __syncthreads();
    }

    int gm0 = bm * BM + wm * 64 + qa * 4;
    int gn0 = bn * BN + wn * 64 + la15;
    #pragma unroll
    for (int mi = 0; mi < 4; mi++) {
        #pragma unroll
        for (int ni = 0; ni < 4; ni++) {
            int gn = gn0 + ni * 16;
            float bsv = bias[gn];
            #pragma unroll
            for (int r2 = 0; r2 < 4; r2++) {
                int gm = gm0 + mi * 16 + r2;
                float v = acc[mi][ni][r2] + bsv;
                if (mode == 0) v = fmaxf(v, 0.f);
                if (mode == 2) {
                    v += bf2f(resid[(size_t)gm * 1024 + gn]);
                    outf[(size_t)gm * 1024 + gn] = v;
                } else {
                    outb[(size_t)gm * 1024 + gn] = f2bf(v);
                }
            }
        }
    }
}

// ---------------------------------------------------------------------------
// LayerNorm(h3 + r) -> r   (one block per row)
// ---------------------------------------------------------------------------
__global__ __launch_bounds__(256) void ln_res(
    const UST* __restrict__ h3, UST* __restrict__ r,
    const float* __restrict__ g, const float* __restrict__ b)
{
    int row = blockIdx.x;
    int t = threadIdx.x;
    int lane = t & 63, wave = t >> 6;
    const ushort4* hp = (const ushort4*)(h3 + (size_t)row * 1024);
    ushort4* rp = (ushort4*)(r + (size_t)row * 1024);
    ushort4 hv = hp[t], rv = rp[t];
    float u0 = bf2f(hv.x) + bf2f(rv.x);
    float u1 = bf2f(hv.y) + bf2f(rv.y);
    float u2 = bf2f(hv.z) + bf2f(rv.z);
    float u3 = bf2f(hv.w) + bf2f(rv.w);

    float s = u0 + u1 + u2 + u3;
    #pragma unroll
    for (int off = 32; off > 0; off >>= 1) s += __shfl_down(s, off, 64);
    __shared__ float red[8];
    if (lane == 0) red[wave] = s;
    __syncthreads();
    float mean = (red[0] + red[1] + red[2] + red[3]) * (1.0f / 1024.0f);

    float d0 = u0 - mean, d1 = u1 - mean, d2 = u2 - mean, d3 = u3 - mean;
    float vs = d0 * d0 + d1 * d1 + d2 * d2 + d3 * d3;
    #pragma unroll
    for (int off = 32; off > 0; off >>= 1) vs += __shfl_down(vs, off, 64);
    if (lane == 0) red[4 + wave] = vs;
    __syncthreads();
    float var = (red[4] + red[5] + red[6] + red[7]) * (1.0f / 1024.0f);
    float rstd = rsqrtf(var + 1e-5f);

    int i0 = t * 4;
    ushort4 o;
    o.x = f2bf(d0 * rstd * g[i0 + 0] + b[i0 + 0]);
    o.y = f2bf(d1 * rstd * g[i0 + 1] + b[i0 + 1]);
    o.z = f2bf(d2 * rstd * g[i0 + 2] + b[i0 + 2]);
    o.w = f2bf(d3 * rstd * g[i0 + 3] + b[i0 + 3]);
    rp[t] = o;
}

// ---------------------------------------------------------------------------
extern "C" void kernel_launch(void* const* d_in, const int* in_sizes, int n_in,
                              void* d_out, int out_size, void* d_ws, size_t ws_size,
                              hipStream_t stream) {
    const float* x     = (const float*)d_in[0];
    const float* scale = (const float*)d_in[1];
    const float* bias  = (const float*)d_in[2];
    const float* la    = (const float*)d_in[3];
    const float* lb    = (const float*)d_in[4];
    const float* ln_w  = (const float*)d_in[5];
    const float* ln_b  = (const float*)d_in[6];
    const int*   qw    = (const int*)d_in[7];

    const int M = in_sizes[0] / 1024;               // 16384
    const size_t WPB = (size_t)18 * 1024 * 1024 * 2;   // 37,748,736 B
    const size_t ACT = (size_t)M * 1024 * 2;           // 33,554,432 B

    UST* wp = (UST*)d_ws;
    UST* A  = (UST*)((char*)d_ws + WPB);            // residual
    UST* Cb = (UST*)((char*)d_ws + WPB + ACT);      // ping
    UST* Bb = (UST*)d_out;                          // pong (dead before fp32 write)

    prep_w<<<dim3(18, 8, 8), 256, 0, stream>>>(qw, scale, la, lb, wp);
    f32_to_bf16<<<(M * 1024) / (256 * 4), 256, 0, stream>>>(x, A);

    int li = 0;
    for (int blk = 0; blk < 6; ++blk) {
        gemm_ep<<<dim3(M / 128, 8), 256, 0, stream>>>(
            A, wp + (size_t)li * 1024 * 1024, bias + li * 1024, Bb, nullptr, nullptr, 0);
        li++;
        gemm_ep<<<dim3(M / 128, 8), 256, 0, stream>>>(
            Bb, wp + (size_t)li * 1024 * 1024, bias + li * 1024, Cb, nullptr, nullptr, 0);
        li++;
        if (blk < 5) {
            gemm_ep<<<dim3(M / 128, 8), 256, 0, stream>>>(
                Cb, wp + (size_t)li * 1024 * 1024, bias + li * 1024, Bb, nullptr, nullptr, 1);
            li++;
            ln_res<<<M, 256, 0, stream>>>(Bb, A, ln_w + blk * 1024, ln_b + blk * 1024);
        } else {
            gemm_ep<<<dim3(M / 128, 8), 256, 0, stream>>>(
                Cb, wp + (size_t)li * 1024 * 1024, bias + li * 1024, nullptr, A,
                (float*)d_out, 2);
            li++;
        }
    }
}

// Round 2
// 1116.735 us; speedup vs baseline: 1.1895x; 1.1895x over previous
//
#include <hip/hip_runtime.h>

typedef unsigned short UST;
typedef __attribute__((ext_vector_type(8))) __bf16 bf16x8;
typedef __attribute__((ext_vector_type(4))) float f32x4;

__device__ __forceinline__ float bf2f(UST u) {
    union { unsigned int i; float f; } v; v.i = ((unsigned int)u) << 16; return v.f;
}
__device__ __forceinline__ UST f2bf(float f) {
    union { float f; unsigned int i; } v; v.f = f;
    return (UST)((v.i + 0x7fffu + ((v.i >> 16) & 1u)) >> 16);
}

__device__ __forceinline__ void gl2lds16(const UST* g, UST* l) {
    __builtin_amdgcn_global_load_lds(
        (const __attribute__((address_space(1))) unsigned int*)g,
        (__attribute__((address_space(3))) unsigned int*)l, 16, 0, 0);
}

// ---------------------------------------------------------------------------
// Weight prep: W'[o,i] = (qw/15*2-1)*scale + sum_r lb[o,r]*la[r,i], cast bf16.
// ---------------------------------------------------------------------------
__global__ __launch_bounds__(256) void prep_w(
    const int* __restrict__ qw, const float* __restrict__ scale,
    const float* __restrict__ la, const float* __restrict__ lb,
    UST* __restrict__ wp)
{
    int l = blockIdx.x, ot = blockIdx.y, it = blockIdx.z;
    __shared__ float la_s[32 * 128];   // [r][i]
    __shared__ float lb_s[128 * 32];   // [o][r]
    const float* laL = la + (size_t)l * 32 * 1024;
    const float* lbL = lb + (size_t)l * 1024 * 32;
    int t = threadIdx.x;
    for (int e = t; e < 32 * 128; e += 256) {
        int r = e >> 7, i = e & 127;
        la_s[e] = laL[r * 1024 + it * 128 + i];
    }
    for (int e = t; e < 128 * 32; e += 256)
        lb_s[e] = lbL[(size_t)ot * 128 * 32 + e];
    __syncthreads();

    int o0 = (t >> 4) * 8;
    int i0 = (t & 15) * 8;
    float acc[8][8];
    #pragma unroll
    for (int a = 0; a < 8; a++)
        #pragma unroll
        for (int c = 0; c < 8; c++) acc[a][c] = 0.f;
    for (int r = 0; r < 32; ++r) {
        float bv[8], av[8];
        #pragma unroll
        for (int j = 0; j < 8; j++) bv[j] = lb_s[(o0 + j) * 32 + r];
        #pragma unroll
        for (int j = 0; j < 8; j++) av[j] = la_s[r * 128 + i0 + j];
        #pragma unroll
        for (int a = 0; a < 8; a++)
            #pragma unroll
            for (int c = 0; c < 8; c++) acc[a][c] += bv[a] * av[c];
    }

    const int* qL = qw + (size_t)l * 1024 * 1024;
    const float* sL = scale + (size_t)l * 1024 * 64;
    UST* wL = wp + (size_t)l * 1024 * 1024;
    #pragma unroll
    for (int a = 0; a < 8; a++) {
        int go = ot * 128 + o0 + a;
        int gi = it * 128 + i0;
        float s = sL[go * 64 + (gi >> 4)];
        UST o8[8];
        #pragma unroll
        for (int c = 0; c < 8; c++) {
            int q = qL[(size_t)go * 1024 + gi + c];
            float w = ((float)q * (2.0f / 15.0f) - 1.0f) * s + acc[a][c];
            o8[c] = f2bf(w);
        }
        *(ushort4*)(wL + (size_t)go * 1024 + gi) = make_ushort4(o8[0], o8[1], o8[2], o8[3]);
        *(ushort4*)(wL + (size_t)go * 1024 + gi + 4) = make_ushort4(o8[4], o8[5], o8[6], o8[7]);
    }
}

__global__ __launch_bounds__(256) void f32_to_bf16(const float* __restrict__ x,
                                                   UST* __restrict__ o)
{
    size_t i = ((size_t)blockIdx.x * 256 + threadIdx.x) * 4;
    float4 v = *(const float4*)(x + i);
    *(ushort4*)(o + i) = make_ushort4(f2bf(v.x), f2bf(v.y), f2bf(v.z), f2bf(v.w));
}

// ---------------------------------------------------------------------------
// GEMM: C[M,1024] = X[M,1024] @ W[1024,1024]^T (+bias, epilogue by mode)
//   mode 0: relu, bf16 out     mode 1: bf16 out     mode 2: +resid, fp32 out
// 128x128 tile, BK=32, 4 waves 2x2, mfma 16x16x32 bf16 4x4/wave.
// 2-stage pipeline: raw s_waitcnt vmcnt(4)+s_barrier so next tile's
// global_load_lds stays in flight across the barrier (m139/AITER pattern).
// LDS k-chunk XOR swizzle kills the 8-way ds_read_b128 conflicts.
// Epilogue transposes through LDS (fp32, bank-swizzled) -> 16B coalesced stores.
// ---------------------------------------------------------------------------
#define BM 128
#define BN 128
#define BK 32

__global__ __launch_bounds__(256, 4) void gemm_ep(
    const UST* __restrict__ X, const UST* __restrict__ W,
    const float* __restrict__ bias,
    UST* __restrict__ outb, const UST* __restrict__ resid,
    float* __restrict__ outf, int mode)
{
    const int K = 1024;
    __shared__ UST smem[16384];   // [buf:2][{A:4096,B:4096}]
    int tid = threadIdx.x;
    int wave = tid >> 6, lane = tid & 63;
    int wm = wave >> 1, wn = wave & 1;
    int bm = blockIdx.x, bn = blockIdx.y;
    int la15 = lane & 15, qa = lane >> 4;

    // staging: chunk c -> LDS granule c; lane fetches the global chunk whose
    // swizzled destination is granule c: row=c>>2, k=(c&3)^((row>>1)&3)
    int c0 = tid, c1 = tid + 256;
    int r0 = c0 >> 2, k0c = ((c0 & 3) ^ ((r0 >> 1) & 3)) * 8;
    int r1 = c1 >> 2, k1c = ((c1 & 3) ^ ((r1 >> 1) & 3)) * 8;
    const UST* gA0 = X + (size_t)(bm * BM + r0) * K + k0c;
    const UST* gA1 = X + (size_t)(bm * BM + r1) * K + k1c;
    const UST* gB0 = W + (size_t)(bn * BN + r0) * K + k0c;
    const UST* gB1 = W + (size_t)(bn * BN + r1) * K + k1c;

    // fragment read offsets (element units), same swizzle
    int offA[4], offB[4];
    #pragma unroll
    for (int i = 0; i < 4; i++) {
        int ra = wm * 64 + i * 16 + la15;
        offA[i] = ra * 32 + ((qa ^ ((ra >> 1) & 3)) * 8);
        int rb = wn * 64 + i * 16 + la15;
        offB[i] = rb * 32 + ((qa ^ ((rb >> 1) & 3)) * 8);
    }

    f32x4 acc[4][4];
    #pragma unroll
    for (int i = 0; i < 4; i++)
        #pragma unroll
        for (int j = 0; j < 4; j++) acc[i][j] = (f32x4){0.f, 0.f, 0.f, 0.f};

    auto issue = [&](int kk, int buf) {
        UST* dA = smem + buf * 8192;
        UST* dB = dA + 4096;
        gl2lds16(gA0 + kk, dA + c0 * 8);
        gl2lds16(gA1 + kk, dA + c1 * 8);
        gl2lds16(gB0 + kk, dB + c0 * 8);
        gl2lds16(gB1 + kk, dB + c1 * 8);
    };
    auto compute = [&](int buf) {
        const UST* pA = smem + buf * 8192;
        const UST* pB = pA + 4096;
        bf16x8 af[4], bfr[4];
        #pragma unroll
        for (int mi = 0; mi < 4; mi++) af[mi] = *(const bf16x8*)&pA[offA[mi]];
        #pragma unroll
        for (int ni = 0; ni < 4; ni++) bfr[ni] = *(const bf16x8*)&pB[offB[ni]];
        #pragma unroll
        for (int mi = 0; mi < 4; mi++)
            #pragma unroll
            for (int ni = 0; ni < 4; ni++)
                acc[mi][ni] = __builtin_amdgcn_mfma_f32_16x16x32_bf16(
                    af[mi], bfr[ni], acc[mi][ni], 0, 0, 0);
    };

    issue(0, 0);
    #pragma unroll 2
    for (int it = 0; it < 31; ++it) {
        int cur = it & 1;
        issue((it + 1) * BK, cur ^ 1);
        asm volatile("s_waitcnt vmcnt(4)\n\ts_barrier" ::: "memory");
        compute(cur);
        asm volatile("s_waitcnt lgkmcnt(0)\n\ts_barrier" ::: "memory");
    }
    asm volatile("s_waitcnt vmcnt(0)\n\ts_barrier" ::: "memory");
    compute(1);
    asm volatile("s_waitcnt lgkmcnt(0)\n\ts_barrier" ::: "memory");

    // ---------------- epilogue: 2 half-tiles (64x128 fp32 = 32 KB) ----------
    float* cs = (float*)smem;
    int cc = tid & 15, rw = tid >> 4;
    int gcolb = bn * BN + cc * 8;
    float4 bv0 = *(const float4*)&bias[gcolb];
    float4 bv1 = *(const float4*)&bias[gcolb + 4];

    #pragma unroll
    for (int h = 0; h < 2; ++h) {
        if (wm == h) {
            #pragma unroll
            for (int mi = 0; mi < 4; mi++)
                #pragma unroll
                for (int ni = 0; ni < 4; ni++) {
                    int colx = (wn * 64 + ni * 16 + la15) ^ (qa << 4);
                    #pragma unroll
                    for (int r2 = 0; r2 < 4; r2++) {
                        int rl = mi * 16 + qa * 4 + r2;
                        cs[rl * 128 + colx] = acc[mi][ni][r2];
                    }
                }
        }
        asm volatile("s_waitcnt lgkmcnt(0)\n\ts_barrier" ::: "memory");
        #pragma unroll
        for (int g = 0; g < 4; ++g) {
            int rl = g * 16 + rw;
            int swz = ((rl >> 2) & 3) << 2;
            int gr0 = ((cc * 2) ^ swz) * 4;
            float4 v0 = *(const float4*)&cs[rl * 128 + gr0];
            float4 v1 = *(const float4*)&cs[rl * 128 + gr0 + 4];
            float o0 = v0.x + bv0.x, o1 = v0.y + bv0.y;
            float o2 = v0.z + bv0.z, o3 = v0.w + bv0.w;
            float o4 = v1.x + bv1.x, o5 = v1.y + bv1.y;
            float o6 = v1.z + bv1.z, o7 = v1.w + bv1.w;
            if (mode == 0) {
                o0 = fmaxf(o0, 0.f); o1 = fmaxf(o1, 0.f);
                o2 = fmaxf(o2, 0.f); o3 = fmaxf(o3, 0.f);
                o4 = fmaxf(o4, 0.f); o5 = fmaxf(o5, 0.f);
                o6 = fmaxf(o6, 0.f); o7 = fmaxf(o7, 0.f);
            }
            int grow = bm * BM + h * 64 + rl;
            size_t base = (size_t)grow * 1024 + gcolb;
            if (mode == 2) {
                ushort4 rv0 = *(const ushort4*)&resid[base];
                ushort4 rv1 = *(const ushort4*)&resid[base + 4];
                o0 += bf2f(rv0.x); o1 += bf2f(rv0.y);
                o2 += bf2f(rv0.z); o3 += bf2f(rv0.w);
                o4 += bf2f(rv1.x); o5 += bf2f(rv1.y);
                o6 += bf2f(rv1.z); o7 += bf2f(rv1.w);
                *(float4*)&outf[base] = make_float4(o0, o1, o2, o3);
                *(float4*)&outf[base + 4] = make_float4(o4, o5, o6, o7);
            } else {
                uint4 pk;
                pk.x = (unsigned)f2bf(o0) | ((unsigned)f2bf(o1) << 16);
                pk.y = (unsigned)f2bf(o2) | ((unsigned)f2bf(o3) << 16);
                pk.z = (unsigned)f2bf(o4) | ((unsigned)f2bf(o5) << 16);
                pk.w = (unsigned)f2bf(o6) | ((unsigned)f2bf(o7) << 16);
                *(uint4*)&outb[base] = pk;
            }
        }
        asm volatile("s_waitcnt lgkmcnt(0)\n\ts_barrier" ::: "memory");
    }
}

// ---------------------------------------------------------------------------
// LayerNorm(h3 + r) -> r   (one block per row)
// ---------------------------------------------------------------------------
__global__ __launch_bounds__(256) void ln_res(
    const UST* __restrict__ h3, UST* __restrict__ r,
    const float* __restrict__ g, const float* __restrict__ b)
{
    int row = blockIdx.x;
    int t = threadIdx.x;
    int lane = t & 63, wave = t >> 6;
    const ushort4* hp = (const ushort4*)(h3 + (size_t)row * 1024);
    ushort4* rp = (ushort4*)(r + (size_t)row * 1024);
    ushort4 hv = hp[t], rv = rp[t];
    float u0 = bf2f(hv.x) + bf2f(rv.x);
    float u1 = bf2f(hv.y) + bf2f(rv.y);
    float u2 = bf2f(hv.z) + bf2f(rv.z);
    float u3 = bf2f(hv.w) + bf2f(rv.w);

    float s = u0 + u1 + u2 + u3;
    #pragma unroll
    for (int off = 32; off > 0; off >>= 1) s += __shfl_down(s, off, 64);
    __shared__ float red[8];
    if (lane == 0) red[wave] = s;
    __syncthreads();
    float mean = (red[0] + red[1] + red[2] + red[3]) * (1.0f / 1024.0f);

    float d0 = u0 - mean, d1 = u1 - mean, d2 = u2 - mean, d3 = u3 - mean;
    float vs = d0 * d0 + d1 * d1 + d2 * d2 + d3 * d3;
    #pragma unroll
    for (int off = 32; off > 0; off >>= 1) vs += __shfl_down(vs, off, 64);
    if (lane == 0) red[4 + wave] = vs;
    __syncthreads();
    float var = (red[4] + red[5] + red[6] + red[7]) * (1.0f / 1024.0f);
    float rstd = rsqrtf(var + 1e-5f);

    int i0 = t * 4;
    ushort4 o;
    o.x = f2bf(d0 * rstd * g[i0 + 0] + b[i0 + 0]);
    o.y = f2bf(d1 * rstd * g[i0 + 1] + b[i0 + 1]);
    o.z = f2bf(d2 * rstd * g[i0 + 2] + b[i0 + 2]);
    o.w = f2bf(d3 * rstd * g[i0 + 3] + b[i0 + 3]);
    rp[t] = o;
}

// ---------------------------------------------------------------------------
extern "C" void kernel_launch(void* const* d_in, const int* in_sizes, int n_in,
                              void* d_out, int out_size, void* d_ws, size_t ws_size,
                              hipStream_t stream) {
    const float* x     = (const float*)d_in[0];
    const float* scale = (const float*)d_in[1];
    const float* bias  = (const float*)d_in[2];
    const float* la    = (const float*)d_in[3];
    const float* lb    = (const float*)d_in[4];
    const float* ln_w  = (const float*)d_in[5];
    const float* ln_b  = (const float*)d_in[6];
    const int*   qw    = (const int*)d_in[7];

    const int M = in_sizes[0] / 1024;                  // 16384
    const size_t WPB = (size_t)18 * 1024 * 1024 * 2;
    const size_t ACT = (size_t)M * 1024 * 2;

    UST* wp = (UST*)d_ws;
    UST* A  = (UST*)((char*)d_ws + WPB);            // residual
    UST* Cb = (UST*)((char*)d_ws + WPB + ACT);      // ping
    UST* Bb = (UST*)d_out;                          // pong (dead before fp32 write)

    prep_w<<<dim3(18, 8, 8), 256, 0, stream>>>(qw, scale, la, lb, wp);
    f32_to_bf16<<<(M * 1024) / (256 * 4), 256, 0, stream>>>(x, A);

    int li = 0;
    for (int blk = 0; blk < 6; ++blk) {
        gemm_ep<<<dim3(M / 128, 8), 256, 0, stream>>>(
            A, wp + (size_t)li * 1024 * 1024, bias + li * 1024, Bb, nullptr, nullptr, 0);
        li++;
        gemm_ep<<<dim3(M / 128, 8), 256, 0, stream>>>(
            Bb, wp + (size_t)li * 1024 * 1024, bias + li * 1024, Cb, nullptr, nullptr, 0);
        li++;
        if (blk < 5) {
            gemm_ep<<<dim3(M / 128, 8), 256, 0, stream>>>(
                Cb, wp + (size_t)li * 1024 * 1024, bias + li * 1024, Bb, nullptr, nullptr, 1);
            li++;
            ln_res<<<M, 256, 0, stream>>>(Bb, A, ln_w + blk * 1024, ln_b + blk * 1024);
        } else {
            gemm_ep<<<dim3(M / 128, 8), 256, 0, stream>>>(
                Cb, wp + (size_t)li * 1024 * 1024, bias + li * 1024, nullptr, A,
                (float*)d_out, 2);
            li++;
        }
    }
}